// Round 7
// baseline (118.431 us; speedup 1.0000x reference)
//
#include <hip/hip_runtime.h>
#include <hip/hip_bf16.h>

// TTCN: h=relu(X@W1+b1); h=relu(h@W2+b2); filt=h@W3+b3; masked softmax over Lx;
// out[n,k]=relu(sum_{l,d} X[n,l,d]*softmax(filt)[n,l,k,d] + T_bias[k])
// N=128, LX=512, D=32, K=63, C=2016.
// R7: TWO kernels. kern_mlp does everything producer-side: in-block mask scan
// (8 ballots), inline weight-fragment gather (weights are L2-hot), MLP via
// bf16 MFMA, compacted Hc/Xt stores, 16-granule pad zeroing, W3fr packing.
// kern_att consumes an n-PAIR per block (W3 frags + reduction amortized 2x).
// Mask compaction: masked rows contribute exactly 0. Pad rows (<=15, zeroed):
// H==0 -> logit==0 -> e==exp2(0)==1.0 exactly -> s accumulated unconditionally,
// scalar pad count subtracted at the end. Biases ride the MFMA K-dim:
// h1[63]=1 & W2 row63=b2 => H[:,63]=1; W3fr row63=b3*log2e (W3 prescaled by
// log2e -> raw v_exp_f32).

#define N_   128
#define LX_  512
#define D_   32
#define K_   63
#define C_   2016
#define LOG2E 1.44269504088896f

typedef __bf16 bf16x8 __attribute__((ext_vector_type(8)));
typedef float floatx4 __attribute__((ext_vector_type(4)));
typedef float floatx2 __attribute__((ext_vector_type(2)));

static __device__ __forceinline__ floatx4 mfma16(bf16x8 a, bf16x8 b, floatx4 c) {
  return __builtin_amdgcn_mfma_f32_16x16x32_bf16(a, b, c, 0, 0, 0);
}

// ws layout (bytes)
#define HC_OFF   0u                        // 128n x 512row x 64 bf16 = 8 MiB (compacted)
#define XT_OFF   (8u * 1024u * 1024u)      // 128n x 32chunk x 32d x 16row f32 = 8 MiB
#define W3FR_OFF (16u * 1024u * 1024u)     // 129024 bf16 frag-packed, *log2e, row63=b3*log2e
#define CNT_OFF  (W3FR_OFF + 262144u)      // 128 i32

// ---------------- M: Hc(bf16, compacted) = MLP(X); Xt planes; W3fr pack ------
// 1024 blocks x 256. Block = 64 tokens of n = bid>>3 (slice blk8 = bid&7).
__global__ __launch_bounds__(256) void kern_mlp(
    const float* __restrict__ X, const float* __restrict__ Mk,
    const float* __restrict__ W1, const float* __restrict__ b1,
    const float* __restrict__ W2, const float* __restrict__ b2,
    const float* __restrict__ W3, const float* __restrict__ b3,
    __bf16* __restrict__ Hc, float* __restrict__ Xt,
    __bf16* __restrict__ W3fr, int* __restrict__ cnt) {
  __shared__ int pos_s[64];
  __shared__ int s_cnt;
  __shared__ float h1s[4][16][68];   // per-wave transpose tile

  const int tid = threadIdx.x;
  const int w = tid >> 6, lane = tid & 63, quad = lane >> 4, l16 = lane & 15;
  const int bid = blockIdx.x;
  const int tok0b = bid * 64;
  const int n = bid >> 3, blk8 = bid & 7;

  // ---- wave 0: mask prefix scan for this n (stores only our 64 rows) ----
  if (tid < 64) {
    int running = 0;
#pragma unroll
    for (int c = 0; c < 8; ++c) {
      const float mkv = Mk[n * LX_ + c * 64 + tid];
      const unsigned long long b = __ballot(mkv > 0.5f);
      const int mypos = running + __popcll(b & ((1ull << tid) - 1ull));
      if (c == blk8) pos_s[tid] = (mkv > 0.5f) ? mypos : -1;
      running += __popcll(b);
    }
    if (tid == 0) {
      s_cnt = running;
      if (blk8 == 0) cnt[n] = running;
    }
  }

  // ---- inline weight-fragment gather (W1/W2/b1/b2 are tiny and L2-hot) ----
  bf16x8 b1f[4], b2f[4][2];
  float b1v[4];
#pragma unroll
  for (int i = 0; i < 4; ++i) {
    const int ch = i * 16 + l16;
    const int chc = (ch < K_) ? ch : 62;
#pragma unroll
    for (int j = 0; j < 8; ++j) {
      const int t = quad * 8 + j;                   // 0..31
      b1f[i][j] = (__bf16)((ch < K_) ? W1[t * K_ + chc] : 0.f);
    }
    b1v[i] = (ch < K_) ? b1[chc] : 0.f;
    const float b2c = (ch < K_) ? b2[chc] : 0.f;
#pragma unroll
    for (int h = 0; h < 2; ++h) {
#pragma unroll
      for (int j = 0; j < 8; ++j) {
        const int t = h * 32 + quad * 8 + j;        // 0..63
        const float w2v = W2[((t < K_) ? t : 62) * K_ + chc];
        float v;
        if (ch < K_) v = (t < K_) ? w2v : b2c;      // row63 = b2
        else         v = (t < K_) ? 0.f : 1.f;      // [63][63]=1 keeps H[:,63]=1
        b2f[i][h][j] = (__bf16)v;
      }
    }
  }

  const int tok0 = tok0b + w * 16;
  const float* xp = X + (size_t)(tok0 + l16) * D_ + quad * 8;
  const float4 xa = *(const float4*)xp;
  const float4 xb = *(const float4*)(xp + 4);
  bf16x8 a1;
  a1[0]=(__bf16)xa.x; a1[1]=(__bf16)xa.y; a1[2]=(__bf16)xa.z; a1[3]=(__bf16)xa.w;
  a1[4]=(__bf16)xb.x; a1[5]=(__bf16)xb.y; a1[6]=(__bf16)xb.z; a1[7]=(__bf16)xb.w;

  __syncthreads();                                  // pos_s/s_cnt ready

  const int px = pos_s[w * 16 + l16];
  const int4 pr4 = *(const int4*)&pos_s[w * 16 + quad * 4];

  if (px >= 0) {  // compacted X f32 d-planes (mask==1 here, so X*mask == X)
    float* xtp = Xt + ((size_t)(n * 32 + (px >> 4)) * 32 + quad * 8) * 16 + (px & 15);
    const float vals[8] = {xa.x, xa.y, xa.z, xa.w, xb.x, xb.y, xb.z, xb.w};
#pragma unroll
    for (int j = 0; j < 8; ++j) xtp[j * 16] = vals[j];
  }

#pragma unroll
  for (int i = 0; i < 4; ++i) {
    floatx4 acc = {0.f, 0.f, 0.f, 0.f};
    acc = mfma16(a1, b1f[i], acc);
#pragma unroll
    for (int r = 0; r < 4; ++r) {
      float v = fmaxf(acc[r] + b1v[i], 0.f);
      if (i == 3 && l16 == 15) v = 1.f;   // h1 col63 := 1 (layer-2 bias row)
      h1s[w][quad * 4 + r][i * 16 + l16] = v;
    }
  }
  // no barrier: h1s[w] is produced and consumed by the same wave (lgkmcnt orders)

  const float* hrow = &h1s[w][l16][0];
  const float4 p0 = *(const float4*)(hrow + quad * 8);
  const float4 p1 = *(const float4*)(hrow + quad * 8 + 4);
  const float4 p2 = *(const float4*)(hrow + 32 + quad * 8);
  const float4 p3 = *(const float4*)(hrow + 32 + quad * 8 + 4);
  bf16x8 a20, a21;
  a20[0]=(__bf16)p0.x; a20[1]=(__bf16)p0.y; a20[2]=(__bf16)p0.z; a20[3]=(__bf16)p0.w;
  a20[4]=(__bf16)p1.x; a20[5]=(__bf16)p1.y; a20[6]=(__bf16)p1.z; a20[7]=(__bf16)p1.w;
  a21[0]=(__bf16)p2.x; a21[1]=(__bf16)p2.y; a21[2]=(__bf16)p2.z; a21[3]=(__bf16)p2.w;
  a21[4]=(__bf16)p3.x; a21[5]=(__bf16)p3.y; a21[6]=(__bf16)p3.z; a21[7]=(__bf16)p3.w;

  const int pr[4] = {pr4.x, pr4.y, pr4.z, pr4.w};
#pragma unroll
  for (int i = 0; i < 4; ++i) {
    floatx4 acc = {0.f, 0.f, 0.f, 0.f};
    acc = mfma16(a20, b2f[i][0], acc);
    acc = mfma16(a21, b2f[i][1], acc);  // bias via k=63 (h1 col63 == 1)
#pragma unroll
    for (int r = 0; r < 4; ++r) {
      if (pr[r] >= 0)
        Hc[((size_t)(n * 512 + pr[r])) * 64 + i * 16 + l16] =
            (__bf16)fmaxf(acc[r], 0.f);
    }
  }

  // ---- pad zeroing of the last 16-granule (<=15 rows), one block per n ----
  if (blk8 == 7) {
    const int c0 = s_cnt, c1 = (c0 + 15) & ~15;
    const float4 z = {0.f, 0.f, 0.f, 0.f};
    for (int idx2 = tid; idx2 < (c1 - c0) * 40; idx2 += 256) {
      const int row = c0 + idx2 / 40, q = idx2 % 40;
      if (q < 8) *(float4*)(Hc + ((size_t)(n * 512 + row)) * 64 + q * 8) = z;
      else Xt[((size_t)(n * 32 + (row >> 4)) * 32 + (q - 8)) * 16 + (row & 15)] = 0.f;
    }
  }

  // ---- W3fr packing side-job (blocks 0..503, one 256-elem slab each) ----
  const int g = bid * 256 + tid;
  if (g < 129024) {   // [tile21][i6][h2][l16][quad][8], *log2e, row63=b3*log2e
    const int j2 = g & 7, q2 = (g >> 3) & 3, l2 = (g >> 5) & 15, h2 = (g >> 9) & 1;
    const int rest = g >> 10, i2 = rest % 6, tile = rest / 6;
    const int c = tile * 96 + i2 * 16 + l2;
    const int t = h2 * 32 + q2 * 8 + j2;
    W3fr[g] = (__bf16)(((t < K_) ? W3[(size_t)t * C_ + c] : b3[c]) * LOG2E);
  }
}

// ---------------- A: fused logits-MFMA + exp2 + pooling, n-PAIR per block ----
// 1344 blocks: xcd=bid&7, g=bid>>3, npl=g&7, bt=g>>3; n0=(xcd*8+npl)*2.
// The 21 tiles of an n-pair land on one XCD (bids spaced 64 -> same %8):
// both Hc slabs (64 KB) stay L2-hot. 16-row chunks round-robin over waves.
__global__ __launch_bounds__(256, 3) void kern_att(
    const __bf16* __restrict__ Hc, const float* __restrict__ Xt,
    const __bf16* __restrict__ W3fr, const int* __restrict__ cnt,
    const float* __restrict__ Tb, float* __restrict__ out) {
  __shared__ float redS[4][192], redO[4][192];
  __shared__ float rbuf[192];

  const int bid = blockIdx.x;
  const int xcd = bid & 7, g = bid >> 3;
  const int npl = g & 7, bt = g >> 3;
  const int n0 = (xcd * 8 + npl) * 2;
  const int tid = threadIdx.x;
  const int w = tid >> 6, lane = tid & 63, quad = lane >> 4, l16 = lane & 15;

  bf16x8 bf[6][2];
#pragma unroll
  for (int i = 0; i < 6; ++i) {
    bf[i][0] = *(const bf16x8*)(W3fr + ((((bt * 6 + i) * 2 + 0) * 16 + l16) * 4 + quad) * 8);
    bf[i][1] = *(const bf16x8*)(W3fr + ((((bt * 6 + i) * 2 + 1) * 16 + l16) * 4 + quad) * 8);
  }

  const int cnt0 = cnt[n0], cnt1 = cnt[n0 + 1];
  const int nch0 = (cnt0 + 15) >> 4, nch1 = (cnt1 + 15) >> 4;
  const int nchm = (nch0 > nch1) ? nch0 : nch1;
  const __bf16* Hb0 = Hc + ((size_t)n0 << 9) * 64 + l16 * 64 + quad * 8;
  const __bf16* Hb1 = Hb0 + (size_t)512 * 64;
  const float*  Xb0 = Xt + (size_t)n0 * 16384 + l16 * 16 + quad * 4;
  const float*  Xb1 = Xb0 + 16384;

  floatx2 s2[2][3], o2[2][3];
#pragma unroll
  for (int ni = 0; ni < 2; ++ni)
#pragma unroll
    for (int t = 0; t < 3; ++t) { s2[ni][t] = {0.f, 0.f}; o2[ni][t] = {0.f, 0.f}; }

#pragma unroll 1
  for (int c = w; c < nchm; c += 4) {
    const bool d0 = c < nch0, d1 = c < nch1;     // wave-uniform
    bf16x8 A0[2], A1[2];
    float4 XL[2], XH[2];
    if (d0) {
      A0[0] = *(const bf16x8*)(Hb0 + (size_t)c * 1024);
      A1[0] = *(const bf16x8*)(Hb0 + (size_t)c * 1024 + 32);
      XL[0] = *(const float4*)(Xb0 + c * 512);
      XH[0] = *(const float4*)(Xb0 + c * 512 + 256);
    }
    if (d1) {
      A0[1] = *(const bf16x8*)(Hb1 + (size_t)c * 1024);
      A1[1] = *(const bf16x8*)(Hb1 + (size_t)c * 1024 + 32);
      XL[1] = *(const float4*)(Xb1 + c * 512);
      XH[1] = *(const float4*)(Xb1 + c * 512 + 256);
    }
#pragma unroll
    for (int ni = 0; ni < 2; ++ni) {
      if (ni ? d1 : d0) {
#pragma unroll
        for (int t = 0; t < 3; ++t) {
          floatx4 accE = {0.f, 0.f, 0.f, 0.f};
          floatx4 accO = {0.f, 0.f, 0.f, 0.f};
          accE = mfma16(A0[ni], bf[2 * t][0], accE);
          accE = mfma16(A1[ni], bf[2 * t][1], accE);   // logit*log2e incl. b3
          accO = mfma16(A0[ni], bf[2 * t + 1][0], accO);
          accO = mfma16(A1[ni], bf[2 * t + 1][1], accO);
#pragma unroll
          for (int r = 0; r < 4; ++r) {
            floatx2 e2, x2;
            e2.x = __builtin_amdgcn_exp2f(accE[r]);
            e2.y = __builtin_amdgcn_exp2f(accO[r]);
            x2.x = XL[ni][r];
            x2.y = XH[ni][r];
            s2[ni][t] += e2;                    // pad rows add exactly 1.0
            o2[ni][t] += e2 * x2;               // pk_fma; x==0 on pad rows
          }
        }
      }
    }
  }

  // reduce the 4 quads (row groups) within each wave
#pragma unroll
  for (int ni = 0; ni < 2; ++ni)
#pragma unroll
    for (int t = 0; t < 3; ++t) {
      s2[ni][t].x += __shfl_xor(s2[ni][t].x, 16); s2[ni][t].x += __shfl_xor(s2[ni][t].x, 32);
      s2[ni][t].y += __shfl_xor(s2[ni][t].y, 16); s2[ni][t].y += __shfl_xor(s2[ni][t].y, 32);
      o2[ni][t].x += __shfl_xor(o2[ni][t].x, 16); o2[ni][t].x += __shfl_xor(o2[ni][t].x, 32);
      o2[ni][t].y += __shfl_xor(o2[ni][t].y, 16); o2[ni][t].y += __shfl_xor(o2[ni][t].y, 32);
    }
  if (quad == 0) {
#pragma unroll
    for (int ni = 0; ni < 2; ++ni)
#pragma unroll
      for (int t = 0; t < 3; ++t) {
        redS[w][ni * 96 + (2 * t) * 16 + l16]     = s2[ni][t].x;
        redS[w][ni * 96 + (2 * t + 1) * 16 + l16] = s2[ni][t].y;
        redO[w][ni * 96 + (2 * t) * 16 + l16]     = o2[ni][t].x;
        redO[w][ni * 96 + (2 * t + 1) * 16 + l16] = o2[ni][t].y;
      }
  }
  __syncthreads();
  if (tid < 192) {
    const int ni = tid / 96;
    const int cc = ni ? cnt1 : cnt0;
    const int nc = ni ? nch1 : nch0;
    const float pad = (float)(nc * 16 - cc);        // exact pad contribution to S
    const float S = redS[0][tid] + redS[1][tid] + redS[2][tid] + redS[3][tid] - pad;
    const float O = redO[0][tid] + redO[1][tid] + redO[2][tid] + redO[3][tid];
    rbuf[tid] = O / S;
  }
  __syncthreads();
  if (tid < 6) {
    const int ni = tid / 3, kk = tid % 3;
    float acc = 0.f;
#pragma unroll
    for (int dd = 0; dd < 32; ++dd) acc += rbuf[ni * 96 + kk * 32 + dd];
    const int k = bt * 3 + kk;
    out[(n0 + ni) * K_ + k] = fmaxf(acc + Tb[k], 0.f);
  }
}

extern "C" void kernel_launch(void* const* d_in, const int* in_sizes, int n_in,
                              void* d_out, int out_size, void* d_ws, size_t ws_size,
                              hipStream_t stream) {
  const float* X  = (const float*)d_in[0];
  const float* Mk = (const float*)d_in[1];
  const float* W1 = (const float*)d_in[2];
  const float* b1 = (const float*)d_in[3];
  const float* W2 = (const float*)d_in[4];
  const float* b2 = (const float*)d_in[5];
  const float* W3 = (const float*)d_in[6];
  const float* b3 = (const float*)d_in[7];
  const float* Tb = (const float*)d_in[8];
  float* out = (float*)d_out;

  char* ws = (char*)d_ws;
  __bf16* Hc   = (__bf16*)(ws + HC_OFF);
  float*  Xt   = (float*)(ws + XT_OFF);
  __bf16* W3fr = (__bf16*)(ws + W3FR_OFF);
  int*    cnt  = (int*)(ws + CNT_OFF);

  kern_mlp<<<1024, 256, 0, stream>>>(X, Mk, W1, b1, W2, b2, W3, b3,
                                     Hc, Xt, W3fr, cnt);
  kern_att<<<1344, 256, 0, stream>>>(Hc, Xt, W3fr, cnt, Tb, out);
}